// Round 1
// baseline (649.927 us; speedup 1.0000x reference)
//
#include <hip/hip_runtime.h>
#include <hip/hip_bf16.h>

#define NN 100000      // nodes
#define NE 1600000     // edges
#define HD 128         // hidden dim
#define NG 64          // graphs
#define NC 10          // classes
#define NCHUNKS 98     // ceil(NN/1024)

// ---------- CSR build ----------
__global__ __launch_bounds__(256) void k_count(const int* __restrict__ dst, int* __restrict__ cnt) {
  int e = blockIdx.x * 256 + threadIdx.x;
  if (e < NE) atomicAdd(&cnt[dst[e]], 1);
}

__global__ __launch_bounds__(256) void k_scan1(const int* __restrict__ cnt, int* __restrict__ rowp,
                                               int* __restrict__ chunkSum, float* __restrict__ dis) {
  __shared__ int sd[256];
  int t = threadIdx.x;
  int base = blockIdx.x * 1024 + t * 4;
  int c0 = (base + 0 < NN) ? cnt[base + 0] : 0;
  int c1 = (base + 1 < NN) ? cnt[base + 1] : 0;
  int c2 = (base + 2 < NN) ? cnt[base + 2] : 0;
  int c3 = (base + 3 < NN) ? cnt[base + 3] : 0;
  if (base + 0 < NN) dis[base + 0] = rsqrtf((float)(c0 + 1));
  if (base + 1 < NN) dis[base + 1] = rsqrtf((float)(c1 + 1));
  if (base + 2 < NN) dis[base + 2] = rsqrtf((float)(c2 + 1));
  if (base + 3 < NN) dis[base + 3] = rsqrtf((float)(c3 + 1));
  int tot = c0 + c1 + c2 + c3;
  sd[t] = tot;
  __syncthreads();
  for (int off = 1; off < 256; off <<= 1) {
    int v = (t >= off) ? sd[t - off] : 0;
    __syncthreads();
    sd[t] += v;
    __syncthreads();
  }
  int excl = sd[t] - tot;
  if (base + 0 < NN) rowp[base + 0] = excl;
  if (base + 1 < NN) rowp[base + 1] = excl + c0;
  if (base + 2 < NN) rowp[base + 2] = excl + c0 + c1;
  if (base + 3 < NN) rowp[base + 3] = excl + c0 + c1 + c2;
  if (t == 255) chunkSum[blockIdx.x] = sd[255];
}

__global__ __launch_bounds__(128) void k_scan2(int* __restrict__ chunkSum, int* __restrict__ rowp) {
  __shared__ int sd[128];
  int t = threadIdx.x;
  int v = (t < NCHUNKS) ? chunkSum[t] : 0;
  sd[t] = v;
  __syncthreads();
  for (int off = 1; off < 128; off <<= 1) {
    int u = (t >= off) ? sd[t - off] : 0;
    __syncthreads();
    sd[t] += u;
    __syncthreads();
  }
  if (t < NCHUNKS) chunkSum[t] = sd[t] - v;   // exclusive
  if (t == NCHUNKS - 1) rowp[NN] = sd[t];     // total = NE
}

__global__ __launch_bounds__(256) void k_scan3(int* __restrict__ rowp, const int* __restrict__ chunkSum) {
  int i = blockIdx.x * 256 + threadIdx.x;
  if (i < NN) rowp[i] += chunkSum[i >> 10];
}

__global__ __launch_bounds__(256) void k_fill(const int* __restrict__ src, const int* __restrict__ dst,
                                              const int* __restrict__ rowp, int* __restrict__ cnt,
                                              int* __restrict__ csr) {
  int e = blockIdx.x * 256 + threadIdx.x;
  if (e < NE) {
    int s = src[e], d = dst[e];
    int pos = atomicSub(&cnt[d], 1) - 1;   // cnt ends at 0 for all nodes
    csr[rowp[d] + pos] = s;
  }
}

// ---------- dense x[Nx128] @ W[128x128] ----------
__global__ __launch_bounds__(256) void k_gemm(const float* __restrict__ X, const float* __restrict__ W,
                                              float* __restrict__ Y) {
  __shared__ float4 WL[64 * 64];  // [k-pair j][feat-pair l] = {W[2j][2l],W[2j][2l+1],W[2j+1][2l],W[2j+1][2l+1]}
  __shared__ float4 XL[32 * 32];  // [row][k-quad]
  int t = threadIdx.x;
  const float2* Wp = (const float2*)W;
  for (int idx = t; idx < 4096; idx += 256) {
    int j = idx >> 6, l = idx & 63;
    float2 a = Wp[(2 * j) * 64 + l];
    float2 b = Wp[(2 * j + 1) * 64 + l];
    WL[idx] = make_float4(a.x, a.y, b.x, b.y);
  }
  size_t rowBase = (size_t)blockIdx.x * 32;
  const float4* Xp = (const float4*)(X + rowBase * HD);
  for (int idx = t; idx < 1024; idx += 256) XL[idx] = Xp[idx];
  __syncthreads();
  int wave = __builtin_amdgcn_readfirstlane(t >> 6);
  int lane = t & 63;
  float accx[8], accy[8];
  #pragma unroll
  for (int r = 0; r < 8; ++r) { accx[r] = 0.f; accy[r] = 0.f; }
  #pragma unroll 4
  for (int j2 = 0; j2 < 32; ++j2) {
    float4 wA = WL[(2 * j2) * 64 + lane];      // k = 4j2, 4j2+1
    float4 wB = WL[(2 * j2 + 1) * 64 + lane];  // k = 4j2+2, 4j2+3
    #pragma unroll
    for (int r = 0; r < 8; ++r) {
      float4 xv = XL[(wave * 8 + r) * 32 + j2];  // wave-uniform broadcast
      accx[r] = fmaf(xv.x, wA.x, accx[r]);
      accy[r] = fmaf(xv.x, wA.y, accy[r]);
      accx[r] = fmaf(xv.y, wA.z, accx[r]);
      accy[r] = fmaf(xv.y, wA.w, accy[r]);
      accx[r] = fmaf(xv.z, wB.x, accx[r]);
      accy[r] = fmaf(xv.z, wB.y, accy[r]);
      accx[r] = fmaf(xv.w, wB.z, accx[r]);
      accy[r] = fmaf(xv.w, wB.w, accy[r]);
    }
  }
  float2* Yp = (float2*)(Y + (rowBase + (size_t)wave * 8) * HD);
  #pragma unroll
  for (int r = 0; r < 8; ++r) {
    float2 o; o.x = accx[r]; o.y = accy[r];
    Yp[r * 64 + lane] = o;
  }
}

// ---------- pull aggregation: one wave per node ----------
__global__ __launch_bounds__(256) void k_agg(const float* __restrict__ XW, const int* __restrict__ rowp,
                                             const int* __restrict__ csr, const float* __restrict__ dis,
                                             const float* __restrict__ bias, float* __restrict__ OUT) {
  int node = __builtin_amdgcn_readfirstlane((blockIdx.x << 2) + (threadIdx.x >> 6));
  int lane = threadIdx.x & 63;
  const float2* xw = (const float2*)XW;
  float di = dis[node];
  float2 a = xw[(size_t)node * 64 + lane];
  float sn = di * di;                       // self-loop norm
  float ax = a.x * sn, ay = a.y * sn;
  int e = rowp[node], end = rowp[node + 1];
  for (; e + 4 <= end; e += 4) {
    int s0 = csr[e], s1 = csr[e + 1], s2 = csr[e + 2], s3 = csr[e + 3];
    float n0 = dis[s0] * di, n1 = dis[s1] * di, n2 = dis[s2] * di, n3 = dis[s3] * di;
    float2 v0 = xw[(size_t)s0 * 64 + lane];
    float2 v1 = xw[(size_t)s1 * 64 + lane];
    float2 v2 = xw[(size_t)s2 * 64 + lane];
    float2 v3 = xw[(size_t)s3 * 64 + lane];
    ax = fmaf(v0.x, n0, ax); ay = fmaf(v0.y, n0, ay);
    ax = fmaf(v1.x, n1, ax); ay = fmaf(v1.y, n1, ay);
    ax = fmaf(v2.x, n2, ax); ay = fmaf(v2.y, n2, ay);
    ax = fmaf(v3.x, n3, ax); ay = fmaf(v3.y, n3, ay);
  }
  for (; e < end; ++e) {
    int s = csr[e];
    float n = dis[s] * di;
    float2 v = xw[(size_t)s * 64 + lane];
    ax = fmaf(v.x, n, ax); ay = fmaf(v.y, n, ay);
  }
  float2 bb = ((const float2*)bias)[lane];
  ax = fmaxf(ax + bb.x, 0.f);
  ay = fmaxf(ay + bb.y, 0.f);
  float2 o; o.x = ax; o.y = ay;
  ((float2*)OUT)[(size_t)node * 64 + lane] = o;
}

// ---------- pooling ----------
__global__ __launch_bounds__(256) void k_bounds(const int* __restrict__ bat, int* __restrict__ sg,
                                                int* __restrict__ eg) {
  int i = blockIdx.x * 256 + threadIdx.x;
  if (i < NN) {
    int g = bat[i];
    if (i == 0 || bat[i - 1] != g) sg[g] = i;
    if (i == NN - 1 || bat[i + 1] != g) eg[g] = i + 1;
  }
}

__global__ __launch_bounds__(128) void k_pool(const float* __restrict__ Hf, const int* __restrict__ sg,
                                              const int* __restrict__ eg, float* __restrict__ sums) {
  int g = blockIdx.x >> 3;
  int sl = blockIdx.x & 7;
  int f = threadIdx.x;
  int s = sg[g], e = eg[g];
  float acc = 0.f;
  for (int n = s + sl; n < e; n += 8) acc += Hf[(size_t)n * HD + f];
  atomicAdd(&sums[g * HD + f], acc);
}

__global__ __launch_bounds__(640) void k_fc(const float* __restrict__ sums, const int* __restrict__ sg,
                                            const int* __restrict__ eg, const float* __restrict__ Wfc,
                                            const float* __restrict__ bfc, float* __restrict__ out) {
  int t = threadIdx.x;
  if (t >= NG * NC) return;
  int g = t / NC, c = t - g * NC;
  int cntn = eg[g] - sg[g];
  float inv = 1.0f / fmaxf((float)cntn, 1.0f);
  float acc = 0.f;
  for (int f = 0; f < HD; ++f) acc = fmaf(sums[g * HD + f], Wfc[f * NC + c], acc);
  out[t] = acc * inv + bfc[c];
}

extern "C" void kernel_launch(void* const* d_in, const int* in_sizes, int n_in,
                              void* d_out, int out_size, void* d_ws, size_t ws_size,
                              hipStream_t stream) {
  const float* x   = (const float*)d_in[0];
  const int*   ei  = (const int*)d_in[1];
  const int*   bat = (const int*)d_in[2];
  const float* W1  = (const float*)d_in[3];
  const float* b1  = (const float*)d_in[4];
  const float* W2  = (const float*)d_in[5];
  const float* b2  = (const float*)d_in[6];
  const float* Wfc = (const float*)d_in[7];
  const float* bfc = (const float*)d_in[8];
  float* out = (float*)d_out;
  const int* esrc = ei;        // edge_index[0]
  const int* edst = ei + NE;   // edge_index[1]

  char* p = (char*)d_ws;
  auto carve = [&](size_t bytes) { char* r = p; p += (bytes + 255) & ~(size_t)255; return r; };
  int*   cnt  = (int*)carve((size_t)NN * 4);
  float* dis  = (float*)carve((size_t)NN * 4);
  int*   rowp = (int*)carve((size_t)(NN + 4) * 4);
  int*   csum = (int*)carve(256 * 4);
  int*   sg   = (int*)carve(NG * 4);
  int*   eg   = (int*)carve(NG * 4);
  float* sums = (float*)carve(NG * HD * 4);
  int*   csr  = (int*)carve((size_t)NE * 4);
  float* A    = (float*)carve((size_t)NN * HD * 4);
  float* B    = (float*)carve((size_t)NN * HD * 4);

  hipMemsetAsync(cnt, 0, (size_t)NN * 4, stream);
  hipMemsetAsync(sums, 0, NG * HD * 4, stream);
  hipMemsetAsync(sg, 0, NG * 4, stream);
  hipMemsetAsync(eg, 0, NG * 4, stream);

  k_count<<<NE / 256, 256, 0, stream>>>(edst, cnt);
  k_scan1<<<NCHUNKS, 256, 0, stream>>>(cnt, rowp, csum, dis);
  k_scan2<<<1, 128, 0, stream>>>(csum, rowp);
  k_scan3<<<(NN + 255) / 256, 256, 0, stream>>>(rowp, csum);
  k_fill<<<NE / 256, 256, 0, stream>>>(esrc, edst, rowp, cnt, csr);

  k_gemm<<<NN / 32, 256, 0, stream>>>(x, W1, A);
  k_agg<<<NN / 4, 256, 0, stream>>>(A, rowp, csr, dis, b1, B);
  k_gemm<<<NN / 32, 256, 0, stream>>>(B, W2, A);
  k_agg<<<NN / 4, 256, 0, stream>>>(A, rowp, csr, dis, b2, B);

  k_bounds<<<(NN + 255) / 256, 256, 0, stream>>>(bat, sg, eg);
  k_pool<<<NG * 8, 128, 0, stream>>>(B, sg, eg, sums);
  k_fc<<<1, 640, 0, stream>>>(sums, sg, eg, Wfc, bfc, out);
}

// Round 4
// 556.871 us; speedup vs baseline: 1.1671x; 1.1671x over previous
//
#include <hip/hip_runtime.h>
#include <hip/hip_bf16.h>

#define NN 100000      // nodes
#define NE 1600000     // edges
#define HD 128         // hidden dim
#define NG 64          // graphs
#define NC 10          // classes
#define NCHUNKS 98     // ceil(NN/1024)
#define NB 391         // dst buckets: b = dst >> 8
#define BCAP 4608      // per-bucket capacity (mean 4092, sigma 64 -> +8 sigma)
#define BSTRIDE 16     // bcnt padding in ints (64B per counter)

__device__ __forceinline__ unsigned pk_bf16(float a, float b) {
  unsigned ua = __float_as_uint(a);
  unsigned ub = __float_as_uint(b);
  unsigned ra = (ua + 0x7fffu + ((ua >> 16) & 1u)) >> 16;  // RNE to bf16
  unsigned rb = (ub + 0x7fffu + ((ub >> 16) & 1u)) >> 16;
  return ra | (rb << 16);
}

// ---------- pass 1: per-node degree count + bucket binning ----------
__global__ __launch_bounds__(256) void k_bin(const int* __restrict__ src, const int* __restrict__ dst,
                                             int* __restrict__ cnt, int* __restrict__ bcnt,
                                             unsigned long long* __restrict__ bkt) {
  int e = blockIdx.x * 256 + threadIdx.x;   // NE % 256 == 0
  int s = src[e], d = dst[e];
  atomicAdd(&cnt[d], 1);
  int b = d >> 8;
  int p = atomicAdd(&bcnt[b * BSTRIDE], 1);
  bkt[(size_t)b * BCAP + p] = ((unsigned long long)(unsigned)d << 32) | (unsigned)s;
}

// ---------- scans: rowp = exclusive prefix of cnt; dis = rsqrt(deg+1) ----------
__global__ __launch_bounds__(256) void k_scan1(const int* __restrict__ cnt, int* __restrict__ rowp,
                                               int* __restrict__ chunkSum, float* __restrict__ dis) {
  __shared__ int sd[256];
  int t = threadIdx.x;
  int base = blockIdx.x * 1024 + t * 4;
  int c0 = (base + 0 < NN) ? cnt[base + 0] : 0;
  int c1 = (base + 1 < NN) ? cnt[base + 1] : 0;
  int c2 = (base + 2 < NN) ? cnt[base + 2] : 0;
  int c3 = (base + 3 < NN) ? cnt[base + 3] : 0;
  if (base + 0 < NN) dis[base + 0] = rsqrtf((float)(c0 + 1));
  if (base + 1 < NN) dis[base + 1] = rsqrtf((float)(c1 + 1));
  if (base + 2 < NN) dis[base + 2] = rsqrtf((float)(c2 + 1));
  if (base + 3 < NN) dis[base + 3] = rsqrtf((float)(c3 + 1));
  int tot = c0 + c1 + c2 + c3;
  sd[t] = tot;
  __syncthreads();
  for (int off = 1; off < 256; off <<= 1) {
    int v = (t >= off) ? sd[t - off] : 0;
    __syncthreads();
    sd[t] += v;
    __syncthreads();
  }
  int excl = sd[t] - tot;
  if (base + 0 < NN) rowp[base + 0] = excl;
  if (base + 1 < NN) rowp[base + 1] = excl + c0;
  if (base + 2 < NN) rowp[base + 2] = excl + c0 + c1;
  if (base + 3 < NN) rowp[base + 3] = excl + c0 + c1 + c2;
  if (t == 255) chunkSum[blockIdx.x] = sd[255];
}

__global__ __launch_bounds__(128) void k_scan2(int* __restrict__ chunkSum, int* __restrict__ rowp) {
  __shared__ int sd[128];
  int t = threadIdx.x;
  int v = (t < NCHUNKS) ? chunkSum[t] : 0;
  sd[t] = v;
  __syncthreads();
  for (int off = 1; off < 128; off <<= 1) {
    int u = (t >= off) ? sd[t - off] : 0;
    __syncthreads();
    sd[t] += u;
    __syncthreads();
  }
  if (t < NCHUNKS) chunkSum[t] = sd[t] - v;   // exclusive
  if (t == NCHUNKS - 1) rowp[NN] = sd[t];     // total = NE
}

__global__ __launch_bounds__(256) void k_scan3(int* __restrict__ rowp, const int* __restrict__ chunkSum) {
  int i = blockIdx.x * 256 + threadIdx.x;
  if (i < NN) rowp[i] += chunkSum[i >> 10];
}

// ---------- pass 2: per-bucket CSR fill (bucket spans are XCD-L2-exclusive) ----------
__global__ __launch_bounds__(256) void k_fill2(const unsigned long long* __restrict__ bkt,
                                               const int* __restrict__ bcnt, const int* __restrict__ rowp,
                                               int* __restrict__ cnt, int* __restrict__ csr) {
  int b = blockIdx.x;
  int n = bcnt[b * BSTRIDE];
  const unsigned long long* mb = bkt + (size_t)b * BCAP;
  for (int i = threadIdx.x; i < n; i += 256) {
    unsigned long long v = mb[i];
    int s = (int)(v & 0xffffffffu);
    int d = (int)(v >> 32);
    int pos = atomicSub(&cnt[d], 1) - 1;   // cnt ends at 0 for all nodes
    csr[rowp[d] + pos] = s;
  }
}

// ---------- dense Ys[n] = dis[n] * (X[Nx128] @ W[128x128]), packed bf16x2 ----------
__global__ __launch_bounds__(256) void k_gemm(const float* __restrict__ X, const float* __restrict__ W,
                                              const float* __restrict__ dis, unsigned* __restrict__ Y) {
  __shared__ float4 WL[64 * 64];  // [k-pair j][feat-pair l]
  __shared__ float4 XL[32 * 32];  // [row][k-quad]
  int t = threadIdx.x;
  const float2* Wp = (const float2*)W;
  for (int idx = t; idx < 4096; idx += 256) {
    int j = idx >> 6, l = idx & 63;
    float2 a = Wp[(2 * j) * 64 + l];
    float2 b = Wp[(2 * j + 1) * 64 + l];
    WL[idx] = make_float4(a.x, a.y, b.x, b.y);
  }
  size_t rowBase = (size_t)blockIdx.x * 32;
  const float4* Xp = (const float4*)(X + rowBase * HD);
  for (int idx = t; idx < 1024; idx += 256) XL[idx] = Xp[idx];
  __syncthreads();
  int wave = __builtin_amdgcn_readfirstlane(t >> 6);
  int lane = t & 63;
  float accx[8], accy[8];
  #pragma unroll
  for (int r = 0; r < 8; ++r) { accx[r] = 0.f; accy[r] = 0.f; }
  #pragma unroll 4
  for (int j2 = 0; j2 < 32; ++j2) {
    float4 wA = WL[(2 * j2) * 64 + lane];      // k = 4j2, 4j2+1
    float4 wB = WL[(2 * j2 + 1) * 64 + lane];  // k = 4j2+2, 4j2+3
    #pragma unroll
    for (int r = 0; r < 8; ++r) {
      float4 xv = XL[(wave * 8 + r) * 32 + j2];  // wave-uniform broadcast
      accx[r] = fmaf(xv.x, wA.x, accx[r]);
      accy[r] = fmaf(xv.x, wA.y, accy[r]);
      accx[r] = fmaf(xv.y, wA.z, accx[r]);
      accy[r] = fmaf(xv.y, wA.w, accy[r]);
      accx[r] = fmaf(xv.z, wB.x, accx[r]);
      accy[r] = fmaf(xv.z, wB.y, accy[r]);
      accx[r] = fmaf(xv.w, wB.z, accx[r]);
      accy[r] = fmaf(xv.w, wB.w, accy[r]);
    }
  }
  unsigned* Yp = Y + (rowBase + (size_t)wave * 8) * 64;
  #pragma unroll
  for (int r = 0; r < 8; ++r) {
    float ds = dis[rowBase + wave * 8 + r];
    Yp[r * 64 + lane] = pk_bf16(accx[r] * ds, accy[r] * ds);
  }
}

// ---------- pull aggregation: one wave per node; Y rows are dis-prescaled bf16 ----------
__global__ __launch_bounds__(256) void k_agg(const unsigned* __restrict__ Y, const int* __restrict__ rowp,
                                             const int* __restrict__ csr, const float* __restrict__ dis,
                                             const float* __restrict__ bias, float* __restrict__ OUT) {
  int node = __builtin_amdgcn_readfirstlane((blockIdx.x << 2) + (threadIdx.x >> 6));
  int lane = threadIdx.x & 63;
  float di = dis[node];
  unsigned a = Y[(size_t)node * 64 + lane];   // self-loop term: di^2*xw = di * Ys[d]
  float ax = __uint_as_float(a << 16);
  float ay = __uint_as_float(a & 0xffff0000u);
  int e = rowp[node], end = rowp[node + 1];
  for (; e + 4 <= end; e += 4) {
    int s0 = csr[e], s1 = csr[e + 1], s2 = csr[e + 2], s3 = csr[e + 3];
    unsigned v0 = Y[(size_t)s0 * 64 + lane];
    unsigned v1 = Y[(size_t)s1 * 64 + lane];
    unsigned v2 = Y[(size_t)s2 * 64 + lane];
    unsigned v3 = Y[(size_t)s3 * 64 + lane];
    ax += __uint_as_float(v0 << 16);          ay += __uint_as_float(v0 & 0xffff0000u);
    ax += __uint_as_float(v1 << 16);          ay += __uint_as_float(v1 & 0xffff0000u);
    ax += __uint_as_float(v2 << 16);          ay += __uint_as_float(v2 & 0xffff0000u);
    ax += __uint_as_float(v3 << 16);          ay += __uint_as_float(v3 & 0xffff0000u);
  }
  for (; e < end; ++e) {
    int s = csr[e];
    unsigned v = Y[(size_t)s * 64 + lane];
    ax += __uint_as_float(v << 16);
    ay += __uint_as_float(v & 0xffff0000u);
  }
  float2 bb = ((const float2*)bias)[lane];
  float2 o;
  o.x = fmaxf(fmaf(di, ax, bb.x), 0.f);
  o.y = fmaxf(fmaf(di, ay, bb.y), 0.f);
  ((float2*)OUT)[(size_t)node * 64 + lane] = o;
}

// ---------- pooling ----------
__global__ __launch_bounds__(256) void k_bounds(const int* __restrict__ bat, int* __restrict__ sg,
                                                int* __restrict__ eg) {
  int i = blockIdx.x * 256 + threadIdx.x;
  if (i < NN) {
    int g = bat[i];
    if (i == 0 || bat[i - 1] != g) sg[g] = i;
    if (i == NN - 1 || bat[i + 1] != g) eg[g] = i + 1;
  }
}

__global__ __launch_bounds__(128) void k_pool(const float* __restrict__ Hf, const int* __restrict__ sg,
                                              const int* __restrict__ eg, float* __restrict__ sums) {
  int g = blockIdx.x >> 3;
  int sl = blockIdx.x & 7;
  int f = threadIdx.x;
  int s = sg[g], e = eg[g];
  float acc = 0.f;
  for (int n = s + sl; n < e; n += 8) acc += Hf[(size_t)n * HD + f];
  atomicAdd(&sums[g * HD + f], acc);
}

__global__ __launch_bounds__(640) void k_fc(const float* __restrict__ sums, const int* __restrict__ sg,
                                            const int* __restrict__ eg, const float* __restrict__ Wfc,
                                            const float* __restrict__ bfc, float* __restrict__ out) {
  int t = threadIdx.x;
  if (t >= NG * NC) return;
  int g = t / NC, c = t - g * NC;
  int cntn = eg[g] - sg[g];
  float inv = 1.0f / fmaxf((float)cntn, 1.0f);
  float acc = 0.f;
  for (int f = 0; f < HD; ++f) acc = fmaf(sums[g * HD + f], Wfc[f * NC + c], acc);
  out[t] = acc * inv + bfc[c];
}

extern "C" void kernel_launch(void* const* d_in, const int* in_sizes, int n_in,
                              void* d_out, int out_size, void* d_ws, size_t ws_size,
                              hipStream_t stream) {
  const float* x   = (const float*)d_in[0];
  const int*   ei  = (const int*)d_in[1];
  const int*   bat = (const int*)d_in[2];
  const float* W1  = (const float*)d_in[3];
  const float* b1  = (const float*)d_in[4];
  const float* W2  = (const float*)d_in[5];
  const float* b2  = (const float*)d_in[6];
  const float* Wfc = (const float*)d_in[7];
  const float* bfc = (const float*)d_in[8];
  float* out = (float*)d_out;
  const int* esrc = ei;        // edge_index[0]
  const int* edst = ei + NE;   // edge_index[1]

  char* p = (char*)d_ws;
  auto carve = [&](size_t bytes) { char* r = p; p += (bytes + 255) & ~(size_t)255; return r; };
  int*   cnt  = (int*)carve((size_t)NN * 4);
  float* dis  = (float*)carve((size_t)NN * 4);
  int*   rowp = (int*)carve((size_t)(NN + 4) * 4);
  int*   csum = (int*)carve(256 * 4);
  int*   sg   = (int*)carve(NG * 4);
  int*   eg   = (int*)carve(NG * 4);
  float* sums = (float*)carve(NG * HD * 4);
  int*   bcnt = (int*)carve((size_t)NB * BSTRIDE * 4);
  int*   csr  = (int*)carve((size_t)NE * 4);
  // YB: bf16x2-packed gemm output (25.6 MB); buckets (14.4 MB) alias it (dead before gemm1)
  unsigned* YB = (unsigned*)carve((size_t)NN * 64 * 4);
  float* H    = (float*)carve((size_t)NN * HD * 4);   // f32 layer output (H1, then H2)
  unsigned long long* bkt = (unsigned long long*)YB;

  hipMemsetAsync(cnt, 0, (size_t)NN * 4, stream);
  hipMemsetAsync(bcnt, 0, (size_t)NB * BSTRIDE * 4, stream);
  hipMemsetAsync(sums, 0, NG * HD * 4, stream);
  hipMemsetAsync(sg, 0, NG * 4, stream);
  hipMemsetAsync(eg, 0, NG * 4, stream);

  k_bin<<<NE / 256, 256, 0, stream>>>(esrc, edst, cnt, bcnt, bkt);
  k_scan1<<<NCHUNKS, 256, 0, stream>>>(cnt, rowp, csum, dis);
  k_scan2<<<1, 128, 0, stream>>>(csum, rowp);
  k_scan3<<<(NN + 255) / 256, 256, 0, stream>>>(rowp, csum);
  k_fill2<<<NB, 256, 0, stream>>>(bkt, bcnt, rowp, cnt, csr);

  k_gemm<<<NN / 32, 256, 0, stream>>>(x, W1, dis, YB);     // YB overwrites dead buckets
  k_agg<<<NN / 4, 256, 0, stream>>>(YB, rowp, csr, dis, b1, H);
  k_gemm<<<NN / 32, 256, 0, stream>>>(H, W2, dis, YB);
  k_agg<<<NN / 4, 256, 0, stream>>>(YB, rowp, csr, dis, b2, H);

  k_bounds<<<(NN + 255) / 256, 256, 0, stream>>>(bat, sg, eg);
  k_pool<<<NG * 8, 128, 0, stream>>>(H, sg, eg, sums);
  k_fc<<<1, 640, 0, stream>>>(sums, sg, eg, Wfc, bfc, out);
}

// Round 7
// 409.480 us; speedup vs baseline: 1.5872x; 1.3599x over previous
//
#include <hip/hip_runtime.h>
#include <hip/hip_bf16.h>

#define NN 100000      // nodes
#define NE 1600000     // edges
#define HD 128         // hidden dim
#define NG 64          // graphs
#define NC 10          // classes
#define NB 391         // dst buckets: b = dst >> 8 (256 nodes per bucket)
#define BCAP 4608      // per-bucket capacity (mean 4096, sigma 64 -> +8 sigma)
#define CHUNK 6400     // edges per k_bin2 block (NE/CHUNK = 250 exactly)

__device__ __forceinline__ unsigned pk_bf16(float a, float b) {
  unsigned ua = __float_as_uint(a);
  unsigned ub = __float_as_uint(b);
  unsigned ra = (ua + 0x7fffu + ((ua >> 16) & 1u)) >> 16;  // RNE to bf16
  unsigned rb = (ub + 0x7fffu + ((ub >> 16) & 1u)) >> 16;
  return ra | (rb << 16);
}

// ---------- pass 1: LDS multi-split binning (block-contiguous runs per bucket) ----------
// bkt entry: packed (s | d_local<<24); s < 2^17, d_local = d & 255.
__global__ __launch_bounds__(256) void k_bin2(const int* __restrict__ src, const int* __restrict__ dst,
                                              int* __restrict__ bcnt, unsigned* __restrict__ bkt) {
  __shared__ int cl[NB];   // per-bucket local count, then local running offset
  __shared__ int cb[NB];   // per-bucket global base for this block's run
  int tid = threadIdx.x;
  int base_e = blockIdx.x * CHUNK;
  for (int i = tid; i < NB; i += 256) cl[i] = 0;
  __syncthreads();
  #pragma unroll 5
  for (int j = 0; j < CHUNK / 256; ++j) {
    int d = dst[base_e + j * 256 + tid];
    atomicAdd(&cl[d >> 8], 1);
  }
  __syncthreads();
  for (int i = tid; i < NB; i += 256) {
    cb[i] = atomicAdd(&bcnt[i], cl[i]);
    cl[i] = 0;
  }
  __syncthreads();
  #pragma unroll 5
  for (int j = 0; j < CHUNK / 256; ++j) {
    int e = base_e + j * 256 + tid;
    int s = src[e];           // L2-hot re-read
    int d = dst[e];
    int b = d >> 8;
    int p = atomicAdd(&cl[b], 1);
    int idx = cb[b] + p;
    if (idx < BCAP)           // statistically impossible overflow guard
      bkt[(size_t)b * BCAP + idx] = (unsigned)s | ((unsigned)(d & 255) << 24);
  }
}

// ---------- pass 2: per-bucket CSR build entirely in LDS ----------
__global__ __launch_bounds__(256) void k_fill2(const unsigned* __restrict__ bkt,
                                               const int* __restrict__ bcnt,
                                               int* __restrict__ rows, int* __restrict__ rowe,
                                               float* __restrict__ dis, int* __restrict__ csr) {
  __shared__ unsigned eds[BCAP];  // 18.4 KB
  __shared__ int sc[256];         // counts -> scan -> scatter offsets
  int b = blockIdx.x;
  int tid = threadIdx.x;
  int n = bcnt[b];
  if (n > BCAP) n = BCAP;
  const unsigned* mb = bkt + (size_t)b * BCAP;
  for (int i = tid; i < n; i += 256) eds[i] = mb[i];
  sc[tid] = 0;
  __syncthreads();
  for (int i = tid; i < n; i += 256) atomicAdd(&sc[eds[i] >> 24], 1);
  __syncthreads();
  int deg = sc[tid];
  // Hillis-Steele inclusive scan over 256 counters
  for (int off = 1; off < 256; off <<= 1) {
    int v = (tid >= off) ? sc[tid - off] : 0;
    __syncthreads();
    sc[tid] += v;
    __syncthreads();
  }
  int excl = sc[tid] - deg;
  int node = b * 256 + tid;
  int cbase = b * BCAP;
  if (node < NN) {
    rows[node] = cbase + excl;
    rowe[node] = cbase + excl + deg;
    dis[node] = rsqrtf((float)(deg + 1));   // +1 self-loop
  }
  __syncthreads();
  sc[tid] = excl;                            // running scatter offset per local node
  __syncthreads();
  for (int i = tid; i < n; i += 256) {
    unsigned v = eds[i];
    int p = atomicAdd(&sc[v >> 24], 1);
    csr[cbase + p] = (int)(v & 0xFFFFFFu);
  }
}

// ---------- dense Ys[n] = dis[n] * (X[Nx128] @ W[128x128]), packed bf16x2 ----------
__global__ __launch_bounds__(256) void k_gemm(const float* __restrict__ X, const float* __restrict__ W,
                                              const float* __restrict__ dis, unsigned* __restrict__ Y) {
  __shared__ float4 WL[64 * 64];  // [k-pair j][feat-pair l]
  __shared__ float4 XL[32 * 32];  // [row][k-quad]
  int t = threadIdx.x;
  const float2* Wp = (const float2*)W;
  for (int idx = t; idx < 4096; idx += 256) {
    int j = idx >> 6, l = idx & 63;
    float2 a = Wp[(2 * j) * 64 + l];
    float2 b = Wp[(2 * j + 1) * 64 + l];
    WL[idx] = make_float4(a.x, a.y, b.x, b.y);
  }
  size_t rowBase = (size_t)blockIdx.x * 32;
  const float4* Xp = (const float4*)(X + rowBase * HD);
  for (int idx = t; idx < 1024; idx += 256) XL[idx] = Xp[idx];
  __syncthreads();
  int wave = __builtin_amdgcn_readfirstlane(t >> 6);
  int lane = t & 63;
  float accx[8], accy[8];
  #pragma unroll
  for (int r = 0; r < 8; ++r) { accx[r] = 0.f; accy[r] = 0.f; }
  #pragma unroll 4
  for (int j2 = 0; j2 < 32; ++j2) {
    float4 wA = WL[(2 * j2) * 64 + lane];      // k = 4j2, 4j2+1
    float4 wB = WL[(2 * j2 + 1) * 64 + lane];  // k = 4j2+2, 4j2+3
    #pragma unroll
    for (int r = 0; r < 8; ++r) {
      float4 xv = XL[(wave * 8 + r) * 32 + j2];  // wave-uniform broadcast
      accx[r] = fmaf(xv.x, wA.x, accx[r]);
      accy[r] = fmaf(xv.x, wA.y, accy[r]);
      accx[r] = fmaf(xv.y, wA.z, accx[r]);
      accy[r] = fmaf(xv.y, wA.w, accy[r]);
      accx[r] = fmaf(xv.z, wB.x, accx[r]);
      accy[r] = fmaf(xv.z, wB.y, accy[r]);
      accx[r] = fmaf(xv.w, wB.z, accx[r]);
      accy[r] = fmaf(xv.w, wB.w, accy[r]);
    }
  }
  unsigned* Yp = Y + (rowBase + (size_t)wave * 8) * 64;
  #pragma unroll
  for (int r = 0; r < 8; ++r) {
    float ds = dis[rowBase + wave * 8 + r];
    Yp[r * 64 + lane] = pk_bf16(accx[r] * ds, accy[r] * ds);
  }
}

// ---------- pull aggregation: one wave per node; Y rows are dis-prescaled bf16 ----------
__global__ __launch_bounds__(256) void k_agg(const unsigned* __restrict__ Y, const int* __restrict__ rows,
                                             const int* __restrict__ rowe, const int* __restrict__ csr,
                                             const float* __restrict__ dis,
                                             const float* __restrict__ bias, float* __restrict__ OUT) {
  int node = __builtin_amdgcn_readfirstlane((blockIdx.x << 2) + (threadIdx.x >> 6));
  int lane = threadIdx.x & 63;
  float di = dis[node];
  unsigned a = Y[(size_t)node * 64 + lane];   // self-loop term: di^2*xw = di * Ys[d]
  float ax = __uint_as_float(a << 16);
  float ay = __uint_as_float(a & 0xffff0000u);
  int e = rows[node], end = rowe[node];
  for (; e + 4 <= end; e += 4) {
    int s0 = csr[e], s1 = csr[e + 1], s2 = csr[e + 2], s3 = csr[e + 3];
    unsigned v0 = Y[(size_t)s0 * 64 + lane];
    unsigned v1 = Y[(size_t)s1 * 64 + lane];
    unsigned v2 = Y[(size_t)s2 * 64 + lane];
    unsigned v3 = Y[(size_t)s3 * 64 + lane];
    ax += __uint_as_float(v0 << 16);          ay += __uint_as_float(v0 & 0xffff0000u);
    ax += __uint_as_float(v1 << 16);          ay += __uint_as_float(v1 & 0xffff0000u);
    ax += __uint_as_float(v2 << 16);          ay += __uint_as_float(v2 & 0xffff0000u);
    ax += __uint_as_float(v3 << 16);          ay += __uint_as_float(v3 & 0xffff0000u);
  }
  for (; e < end; ++e) {
    int s = csr[e];
    unsigned v = Y[(size_t)s * 64 + lane];
    ax += __uint_as_float(v << 16);
    ay += __uint_as_float(v & 0xffff0000u);
  }
  float2 bb = ((const float2*)bias)[lane];
  float2 o;
  o.x = fmaxf(fmaf(di, ax, bb.x), 0.f);
  o.y = fmaxf(fmaf(di, ay, bb.y), 0.f);
  ((float2*)OUT)[(size_t)node * 64 + lane] = o;
}

// ---------- pooling ----------
__global__ __launch_bounds__(256) void k_bounds(const int* __restrict__ bat, int* __restrict__ sg,
                                                int* __restrict__ eg) {
  int i = blockIdx.x * 256 + threadIdx.x;
  if (i < NN) {
    int g = bat[i];
    if (i == 0 || bat[i - 1] != g) sg[g] = i;
    if (i == NN - 1 || bat[i + 1] != g) eg[g] = i + 1;
  }
}

__global__ __launch_bounds__(128) void k_pool(const float* __restrict__ Hf, const int* __restrict__ sg,
                                              const int* __restrict__ eg, float* __restrict__ sums) {
  int g = blockIdx.x >> 3;
  int sl = blockIdx.x & 7;
  int f = threadIdx.x;
  int s = sg[g], e = eg[g];
  float acc = 0.f;
  for (int n = s + sl; n < e; n += 8) acc += Hf[(size_t)n * HD + f];
  atomicAdd(&sums[g * HD + f], acc);
}

__global__ __launch_bounds__(640) void k_fc(const float* __restrict__ sums, const int* __restrict__ sg,
                                            const int* __restrict__ eg, const float* __restrict__ Wfc,
                                            const float* __restrict__ bfc, float* __restrict__ out) {
  int t = threadIdx.x;
  if (t >= NG * NC) return;
  int g = t / NC, c = t - g * NC;
  int cntn = eg[g] - sg[g];
  float inv = 1.0f / fmaxf((float)cntn, 1.0f);
  float acc = 0.f;
  for (int f = 0; f < HD; ++f) acc = fmaf(sums[g * HD + f], Wfc[f * NC + c], acc);
  out[t] = acc * inv + bfc[c];
}

extern "C" void kernel_launch(void* const* d_in, const int* in_sizes, int n_in,
                              void* d_out, int out_size, void* d_ws, size_t ws_size,
                              hipStream_t stream) {
  const float* x   = (const float*)d_in[0];
  const int*   ei  = (const int*)d_in[1];
  const int*   bat = (const int*)d_in[2];
  const float* W1  = (const float*)d_in[3];
  const float* b1  = (const float*)d_in[4];
  const float* W2  = (const float*)d_in[5];
  const float* b2  = (const float*)d_in[6];
  const float* Wfc = (const float*)d_in[7];
  const float* bfc = (const float*)d_in[8];
  float* out = (float*)d_out;
  const int* esrc = ei;        // edge_index[0]
  const int* edst = ei + NE;   // edge_index[1]

  char* p = (char*)d_ws;
  auto carve = [&](size_t bytes) { char* r = p; p += (bytes + 255) & ~(size_t)255; return r; };
  float* dis  = (float*)carve((size_t)NN * 4);
  int*   rows = (int*)carve((size_t)NN * 4);
  int*   rowe = (int*)carve((size_t)NN * 4);
  int*   bcnt = (int*)carve((size_t)NB * 4);
  int*   sg   = (int*)carve(NG * 4);
  int*   eg   = (int*)carve(NG * 4);
  float* sums = (float*)carve(NG * HD * 4);
  int*   csr  = (int*)carve((size_t)NB * BCAP * 4);   // 7.2 MB, [NB][BCAP] layout
  // YB: bf16x2-packed gemm output (25.6 MB); bkt (7.2 MB) aliases it (dead before gemm1)
  unsigned* YB = (unsigned*)carve((size_t)NN * 64 * 4);
  float* H    = (float*)carve((size_t)NN * HD * 4);   // f32 layer output (H1, then H2)
  unsigned* bkt = YB;

  hipMemsetAsync(bcnt, 0, (size_t)NB * 4, stream);
  hipMemsetAsync(sums, 0, NG * HD * 4, stream);
  hipMemsetAsync(sg, 0, NG * 4, stream);
  hipMemsetAsync(eg, 0, NG * 4, stream);

  k_bin2<<<NE / CHUNK, 256, 0, stream>>>(esrc, edst, bcnt, bkt);
  k_fill2<<<NB, 256, 0, stream>>>(bkt, bcnt, rows, rowe, dis, csr);

  k_gemm<<<NN / 32, 256, 0, stream>>>(x, W1, dis, YB);     // YB overwrites dead bkt
  k_agg<<<NN / 4, 256, 0, stream>>>(YB, rows, rowe, csr, dis, b1, H);
  k_gemm<<<NN / 32, 256, 0, stream>>>(H, W2, dis, YB);
  k_agg<<<NN / 4, 256, 0, stream>>>(YB, rows, rowe, csr, dis, b2, H);

  k_bounds<<<(NN + 255) / 256, 256, 0, stream>>>(bat, sg, eg);
  k_pool<<<NG * 8, 128, 0, stream>>>(H, sg, eg, sums);
  k_fc<<<1, 640, 0, stream>>>(sums, sg, eg, Wfc, bfc, out);
}

// Round 8
// 259.604 us; speedup vs baseline: 2.5035x; 1.5773x over previous
//
#include <hip/hip_runtime.h>
#include <hip/hip_bf16.h>

#define NN 100000      // nodes
#define NE 1600000     // edges
#define HD 128         // hidden dim
#define NG 64          // graphs
#define NC 10          // classes
#define NB 391         // dst buckets: b = dst >> 8 (256 nodes per bucket)
#define BCAP 4608      // per-bucket capacity (mean 4096, sigma 64 -> +8 sigma)
#define CHUNK 6400     // edges per k_bin2 block (NE/CHUNK = 250 exactly)

typedef short bf16x8 __attribute__((ext_vector_type(8)));
typedef float f32x4 __attribute__((ext_vector_type(4)));

__device__ __forceinline__ unsigned pk_bf16(float a, float b) {
  unsigned ua = __float_as_uint(a);
  unsigned ub = __float_as_uint(b);
  unsigned ra = (ua + 0x7fffu + ((ua >> 16) & 1u)) >> 16;  // RNE to bf16
  unsigned rb = (ub + 0x7fffu + ((ub >> 16) & 1u)) >> 16;
  return ra | (rb << 16);
}

// ---------- pass 1: LDS multi-split binning ----------
__global__ __launch_bounds__(256) void k_bin2(const int* __restrict__ src, const int* __restrict__ dst,
                                              int* __restrict__ bcnt, unsigned* __restrict__ bkt) {
  __shared__ int cl[NB];
  __shared__ int cb[NB];
  int tid = threadIdx.x;
  int base_e = blockIdx.x * CHUNK;
  for (int i = tid; i < NB; i += 256) cl[i] = 0;
  __syncthreads();
  #pragma unroll 5
  for (int j = 0; j < CHUNK / 256; ++j) {
    int d = dst[base_e + j * 256 + tid];
    atomicAdd(&cl[d >> 8], 1);
  }
  __syncthreads();
  for (int i = tid; i < NB; i += 256) {
    cb[i] = atomicAdd(&bcnt[i], cl[i]);
    cl[i] = 0;
  }
  __syncthreads();
  #pragma unroll 5
  for (int j = 0; j < CHUNK / 256; ++j) {
    int e = base_e + j * 256 + tid;
    int s = src[e];
    int d = dst[e];
    int b = d >> 8;
    int p = atomicAdd(&cl[b], 1);
    int idx = cb[b] + p;
    if (idx < BCAP)
      bkt[(size_t)b * BCAP + idx] = (unsigned)s | ((unsigned)(d & 255) << 24);
  }
}

// ---------- pass 2: per-bucket CSR build entirely in LDS ----------
__global__ __launch_bounds__(256) void k_fill2(const unsigned* __restrict__ bkt,
                                               const int* __restrict__ bcnt,
                                               int* __restrict__ rows, int* __restrict__ rowe,
                                               float* __restrict__ dis, int* __restrict__ csr) {
  __shared__ unsigned eds[BCAP];
  __shared__ int sc[256];
  int b = blockIdx.x;
  int tid = threadIdx.x;
  int n = bcnt[b];
  if (n > BCAP) n = BCAP;
  const unsigned* mb = bkt + (size_t)b * BCAP;
  for (int i = tid; i < n; i += 256) eds[i] = mb[i];
  sc[tid] = 0;
  __syncthreads();
  for (int i = tid; i < n; i += 256) atomicAdd(&sc[eds[i] >> 24], 1);
  __syncthreads();
  int deg = sc[tid];
  for (int off = 1; off < 256; off <<= 1) {
    int v = (tid >= off) ? sc[tid - off] : 0;
    __syncthreads();
    sc[tid] += v;
    __syncthreads();
  }
  int excl = sc[tid] - deg;
  int node = b * 256 + tid;
  int cbase = b * BCAP;
  if (node < NN) {
    rows[node] = cbase + excl;
    rowe[node] = cbase + excl + deg;
    dis[node] = rsqrtf((float)(deg + 1));
  }
  __syncthreads();
  sc[tid] = excl;
  __syncthreads();
  for (int i = tid; i < n; i += 256) {
    unsigned v = eds[i];
    int p = atomicAdd(&sc[v >> 24], 1);
    csr[cbase + p] = (int)(v & 0xFFFFFFu);
  }
}

// ---------- W prep: WT[n][k] bf16-pair packed, from W[k][n] f32 ----------
__global__ __launch_bounds__(256) void k_prepW(const float* __restrict__ W1, const float* __restrict__ W2,
                                               unsigned* __restrict__ WT1, unsigned* __restrict__ WT2) {
  int i = blockIdx.x * 256 + threadIdx.x;   // 64 blocks: first 32 -> W1, rest -> W2
  const float* W = (i < 8192) ? W1 : W2;
  unsigned* WT = (i < 8192) ? WT1 : WT2;
  int j = i & 8191;
  int n = j >> 6, kh = j & 63;              // kh = k/2
  WT[j] = pk_bf16(W[(2 * kh) * HD + n], W[(2 * kh + 1) * HD + n]);
}

// ---------- MFMA GEMM: Y[node] = dis[node] * (X @ W), bf16x2-packed out ----------
// A = W^T (from WT[n][k]), B = X^T (node-major rows are k-contiguous).
// D[i=n][j=node]; per wave: 16 nodes x 128 cols, K=128 via 4 mfma_16x16x32 steps.
template<bool BF16IN>
__global__ __launch_bounds__(256) void k_gemm_mfma(const void* __restrict__ Xin,
                                                   const unsigned* __restrict__ WT,
                                                   const float* __restrict__ dis,
                                                   unsigned* __restrict__ Y) {
  __shared__ char WL[128 * 256];  // [n][k] bf16, XOR-swizzled
  __shared__ char XL[64 * 256];   // [node][k] bf16, XOR-swizzled
  int t = threadIdx.x;
  int rowBase = blockIdx.x * 64;
  {
    const uint4* Wg = (const uint4*)WT;   // 2048 uint4
    for (int i = t; i < 2048; i += 256) {
      int n = i >> 4, kq = i & 15;
      uint4 v = Wg[i];
      *(uint4*)(WL + ((n * 256 + kq * 16) ^ ((n & 7) << 4))) = v;
    }
  }
  if (BF16IN) {
    const uint4* Xg = (const uint4*)Xin;  // [node][16] uint4
    for (int i = t; i < 1024; i += 256) {
      int node = i >> 4, c = i & 15;
      int gn = rowBase + node; if (gn >= NN) gn = 0;
      uint4 v = Xg[(size_t)gn * 16 + c];
      *(uint4*)(XL + ((node * 256 + c * 16) ^ ((node & 7) << 4))) = v;
    }
  } else {
    const float4* Xg = (const float4*)Xin; // [node][32] float4
    for (int i = t; i < 1024; i += 256) {
      int node = i >> 4, c = i & 15;
      int gn = rowBase + node; if (gn >= NN) gn = 0;
      float4 a = Xg[(size_t)gn * 32 + c * 2];
      float4 b = Xg[(size_t)gn * 32 + c * 2 + 1];
      uint4 v;
      v.x = pk_bf16(a.x, a.y); v.y = pk_bf16(a.z, a.w);
      v.z = pk_bf16(b.x, b.y); v.w = pk_bf16(b.z, b.w);
      *(uint4*)(XL + ((node * 256 + c * 16) ^ ((node & 7) << 4))) = v;
    }
  }
  __syncthreads();
  int w = t >> 6, l = t & 63;
  int lr = l & 15, lh = l >> 4;
  int xnode = w * 16 + lr;
  bf16x8 bfrag[4];
  #pragma unroll
  for (int ks = 0; ks < 4; ++ks)
    bfrag[ks] = *(bf16x8*)(XL + ((xnode * 256 + (ks * 32 + lh * 8) * 2) ^ ((xnode & 7) << 4)));
  f32x4 acc[8];
  #pragma unroll
  for (int ct = 0; ct < 8; ++ct) acc[ct] = (f32x4){0.f, 0.f, 0.f, 0.f};
  #pragma unroll
  for (int ct = 0; ct < 8; ++ct) {
    int n = ct * 16 + lr;
    #pragma unroll
    for (int ks = 0; ks < 4; ++ks) {
      bf16x8 af = *(bf16x8*)(WL + ((n * 256 + (ks * 32 + lh * 8) * 2) ^ ((n & 7) << 4)));
      acc[ct] = __builtin_amdgcn_mfma_f32_16x16x32_bf16(af, bfrag[ks], acc[ct], 0, 0, 0);
    }
  }
  int gnode = rowBase + w * 16 + lr;
  if (gnode < NN) {
    float ds = dis[gnode];
    uint2* Yp = (uint2*)(Y + (size_t)gnode * 64);
    #pragma unroll
    for (int ct = 0; ct < 8; ++ct) {
      uint2 o;
      o.x = pk_bf16(acc[ct].x * ds, acc[ct].y * ds);
      o.y = pk_bf16(acc[ct].z * ds, acc[ct].w * ds);
      Yp[ct * 4 + lh] = o;   // n = ct*16 + lh*4 + {0..3}
    }
  }
}

// ---------- pull aggregation: one wave per node; Y rows are dis-prescaled bf16 ----------
// MODE 0: OUT = packed bf16x2 (u32[node][64]); MODE 1: OUT = f32 (float2[node][64])
template<int MODE>
__global__ __launch_bounds__(256) void k_agg(const unsigned* __restrict__ Y, const int* __restrict__ rows,
                                             const int* __restrict__ rowe, const int* __restrict__ csr,
                                             const float* __restrict__ dis,
                                             const float* __restrict__ bias, void* __restrict__ OUT) {
  int node = __builtin_amdgcn_readfirstlane((blockIdx.x << 2) + (threadIdx.x >> 6));
  int lane = threadIdx.x & 63;
  float di = dis[node];
  unsigned a = Y[(size_t)node * 64 + lane];   // self-loop term: di^2*xw = di * Ys[d]
  float ax = __uint_as_float(a << 16);
  float ay = __uint_as_float(a & 0xffff0000u);
  int e = rows[node], end = rowe[node];
  for (; e + 4 <= end; e += 4) {
    int s0 = csr[e], s1 = csr[e + 1], s2 = csr[e + 2], s3 = csr[e + 3];
    unsigned v0 = Y[(size_t)s0 * 64 + lane];
    unsigned v1 = Y[(size_t)s1 * 64 + lane];
    unsigned v2 = Y[(size_t)s2 * 64 + lane];
    unsigned v3 = Y[(size_t)s3 * 64 + lane];
    ax += __uint_as_float(v0 << 16);          ay += __uint_as_float(v0 & 0xffff0000u);
    ax += __uint_as_float(v1 << 16);          ay += __uint_as_float(v1 & 0xffff0000u);
    ax += __uint_as_float(v2 << 16);          ay += __uint_as_float(v2 & 0xffff0000u);
    ax += __uint_as_float(v3 << 16);          ay += __uint_as_float(v3 & 0xffff0000u);
  }
  for (; e < end; ++e) {
    int s = csr[e];
    unsigned v = Y[(size_t)s * 64 + lane];
    ax += __uint_as_float(v << 16);
    ay += __uint_as_float(v & 0xffff0000u);
  }
  float2 bb = ((const float2*)bias)[lane];
  float ox = fmaxf(fmaf(di, ax, bb.x), 0.f);
  float oy = fmaxf(fmaf(di, ay, bb.y), 0.f);
  if (MODE == 0) {
    ((unsigned*)OUT)[(size_t)node * 64 + lane] = pk_bf16(ox, oy);
  } else {
    float2 o; o.x = ox; o.y = oy;
    ((float2*)OUT)[(size_t)node * 64 + lane] = o;
  }
}

// ---------- pooling ----------
__global__ __launch_bounds__(256) void k_bounds(const int* __restrict__ bat, int* __restrict__ sg,
                                                int* __restrict__ eg) {
  int i = blockIdx.x * 256 + threadIdx.x;
  if (i < NN) {
    int g = bat[i];
    if (i == 0 || bat[i - 1] != g) sg[g] = i;
    if (i == NN - 1 || bat[i + 1] != g) eg[g] = i + 1;
  }
}

__global__ __launch_bounds__(128) void k_pool(const float* __restrict__ Hf, const int* __restrict__ sg,
                                              const int* __restrict__ eg, float* __restrict__ sums) {
  int g = blockIdx.x >> 5;
  int sl = blockIdx.x & 31;
  int f = threadIdx.x;
  int s = sg[g], e = eg[g];
  float acc = 0.f;
  for (int n = s + sl; n < e; n += 32) acc += Hf[(size_t)n * HD + f];
  atomicAdd(&sums[g * HD + f], acc);
}

__global__ __launch_bounds__(640) void k_fc(const float* __restrict__ sums, const int* __restrict__ sg,
                                            const int* __restrict__ eg, const float* __restrict__ Wfc,
                                            const float* __restrict__ bfc, float* __restrict__ out) {
  int t = threadIdx.x;
  if (t >= NG * NC) return;
  int g = t / NC, c = t - g * NC;
  int cntn = eg[g] - sg[g];
  float inv = 1.0f / fmaxf((float)cntn, 1.0f);
  float acc = 0.f;
  for (int f = 0; f < HD; ++f) acc = fmaf(sums[g * HD + f], Wfc[f * NC + c], acc);
  out[t] = acc * inv + bfc[c];
}

extern "C" void kernel_launch(void* const* d_in, const int* in_sizes, int n_in,
                              void* d_out, int out_size, void* d_ws, size_t ws_size,
                              hipStream_t stream) {
  const float* x   = (const float*)d_in[0];
  const int*   ei  = (const int*)d_in[1];
  const int*   bat = (const int*)d_in[2];
  const float* W1  = (const float*)d_in[3];
  const float* b1  = (const float*)d_in[4];
  const float* W2  = (const float*)d_in[5];
  const float* b2  = (const float*)d_in[6];
  const float* Wfc = (const float*)d_in[7];
  const float* bfc = (const float*)d_in[8];
  float* out = (float*)d_out;
  const int* esrc = ei;        // edge_index[0]
  const int* edst = ei + NE;   // edge_index[1]

  char* p = (char*)d_ws;
  auto carve = [&](size_t bytes) { char* r = p; p += (bytes + 255) & ~(size_t)255; return r; };
  float* dis  = (float*)carve((size_t)NN * 4);
  int*   rows = (int*)carve((size_t)NN * 4);
  int*   rowe = (int*)carve((size_t)NN * 4);
  int*   bcnt = (int*)carve((size_t)NB * 4);
  int*   sg   = (int*)carve(NG * 4);
  int*   eg   = (int*)carve(NG * 4);
  float* sums = (float*)carve(NG * HD * 4);
  unsigned* WT1 = (unsigned*)carve(8192 * 4);
  unsigned* WT2 = (unsigned*)carve(8192 * 4);
  int*   csr  = (int*)carve((size_t)NB * BCAP * 4);     // 7.2 MB
  unsigned* Y   = (unsigned*)carve((size_t)NN * 64 * 4);  // 25.6 MB; bkt aliases (dead before gemm1)
  unsigned* H1b = (unsigned*)carve((size_t)NN * 64 * 4);  // 25.6 MB, layer-1 output bf16
  float* H2   = (float*)carve((size_t)NN * HD * 4);       // 51.2 MB, layer-2 output f32
  unsigned* bkt = Y;

  hipMemsetAsync(bcnt, 0, (size_t)NB * 4, stream);
  hipMemsetAsync(sums, 0, NG * HD * 4, stream);
  hipMemsetAsync(sg, 0, NG * 4, stream);
  hipMemsetAsync(eg, 0, NG * 4, stream);

  k_bin2<<<NE / CHUNK, 256, 0, stream>>>(esrc, edst, bcnt, bkt);
  k_fill2<<<NB, 256, 0, stream>>>(bkt, bcnt, rows, rowe, dis, csr);
  k_prepW<<<64, 256, 0, stream>>>(W1, W2, WT1, WT2);

  int gblocks = (NN + 63) / 64;
  k_gemm_mfma<false><<<gblocks, 256, 0, stream>>>(x, WT1, dis, Y);
  k_agg<0><<<NN / 4, 256, 0, stream>>>(Y, rows, rowe, csr, dis, b1, H1b);
  k_gemm_mfma<true><<<gblocks, 256, 0, stream>>>(H1b, WT2, dis, Y);
  k_agg<1><<<NN / 4, 256, 0, stream>>>(Y, rows, rowe, csr, dis, b2, H2);

  k_bounds<<<(NN + 255) / 256, 256, 0, stream>>>(bat, sg, eg);
  k_pool<<<NG * 32, 128, 0, stream>>>(H2, sg, eg, sums);
  k_fc<<<1, 640, 0, stream>>>(sums, sg, eg, Wfc, bfc, out);
}